// Round 4
// baseline (424.286 us; speedup 1.0000x reference)
//
#include <hip/hip_runtime.h>

// PhiSoftMax: fused causal attention + Gumbel-sigmoid DAG mask, MI355X gfx950.
// R3: R2 structure (precomputed bf16 dag, no-max attn softmax, in-block merge)
// + per-row max-shift folded into the stored dag (softmax shift invariance):
// mask_k pass1 computes row max M of d over open entries (d monotone in g+phi),
// pass2 stores bf16(d - M). Argmax entry -> 0, so attn's exp never underflows
// a whole row (R2's NaN). attn_main unchanged from R2. ws usage ~45.6 MB.

#define Bz 2
#define Lz 2048
#define Sz 2048
#define Hz 8
#define Ez 64

typedef __attribute__((ext_vector_type(8))) short short8;   // 8 bf16 (4 VGPRs)
typedef __attribute__((ext_vector_type(4))) short short4v;  // 4 bf16 (8B)
typedef __attribute__((ext_vector_type(4))) float f32x4;    // MFMA C/D frag

__device__ __forceinline__ float fast_rcp(float x) { return __builtin_amdgcn_rcpf(x); }

// float -> bf16 bits, round-to-nearest-even (finite inputs only)
__device__ __forceinline__ short f2bf(float x) {
    unsigned bits = __builtin_bit_cast(unsigned, x);
    bits += 0x7FFFu + ((bits >> 16) & 1u);
    return (short)(bits >> 16);
}

// packed-causal tile offset: S(c) = sum_{c'<c} (floor(c'/4)+1), tiles of 16x64
__device__ __forceinline__ int tile_base_of_chunk(int c, int causal) {
    if (!causal) return c * 32;
    const int g = c >> 2, r = c & 3;
    return 2*g*(g-1) + g*r + c;
}

// ---------------- prepack: Q (scaled by 1/8) and K to bf16 [b,h,l,e] ----------------
__global__ void pack_qk(const float* __restrict__ q, const float* __restrict__ k,
                        short* __restrict__ qp, short* __restrict__ kp)
{
    const int t = blockIdx.x * 256 + threadIdx.x;   // 524288 float4 slots
    const float4 qv = ((const float4*)q)[t];
    const float4 kv = ((const float4*)k)[t];
    const int e4   = t & 15;
    const int rest = t >> 4;          // (b*L + l)*H + h
    const int h    = rest & 7;
    const int bl   = rest >> 3;
    const int b    = bl >> 11;
    const int l    = bl & 2047;
    const int o    = ((b*Hz + h)*Lz + l)*Ez + e4*4;
    short4v qo, ko;
    qo[0] = f2bf(qv.x*0.125f); qo[1] = f2bf(qv.y*0.125f);
    qo[2] = f2bf(qv.z*0.125f); qo[3] = f2bf(qv.w*0.125f);
    ko[0] = f2bf(kv.x); ko[1] = f2bf(kv.y); ko[2] = f2bf(kv.z); ko[3] = f2bf(kv.w);
    *(short4v*)&qp[o] = qo;
    *(short4v*)&kp[o] = ko;
}

// ---------------- prepack: V transposed to bf16 [b,h,e,s] ----------------
__global__ void pack_vt(const float* __restrict__ v, short* __restrict__ vt)
{
    const int blk = blockIdx.x;        // 1024 blocks: (b, h, s-tile of 32)
    const int st  = blk & 63;
    const int h   = (blk >> 6) & 7;
    const int b   = blk >> 9;
    const int s0  = st * 32;
    const int e   = threadIdx.x & 63;
    const int sc  = threadIdx.x >> 6;
    short8 ov;
#pragma unroll
    for (int j = 0; j < 8; ++j) {
        const int s = s0 + sc*8 + j;
        ov[j] = f2bf(v[((b*Sz + s)*Hz + h)*Ez + e]);
    }
    *(short8*)&vt[((b*Hz + h)*Ez + e)*Sz + s0 + sc*8] = ov;
}

// ---------------- mask kernel: dag = 1250*min(sigmoid((g+phi)/tau)-thr,0) - rowmax ----------------
// One block per (h, chunk of 16 rows). Pass 1: per-row max M over open entries
// (exact: d is monotone in g+phi, but we reduce on d directly). Pass 2: re-read
// (L2-hot, reverse order) and store bf16(d - M); closed -> -inf (0xFF80).
__global__ __launch_bounds__(256) void mask_k(
    const float* __restrict__ phi, const float* __restrict__ u,
    const int* __restrict__ hm, const int* __restrict__ causal_p,
    const float* __restrict__ log_tau_p, const float* __restrict__ thr_p,
    unsigned short* __restrict__ dag)
{
    const int h = blockIdx.x & 7;               // XCD affinity
    const int c = 127 - (blockIdx.x >> 3);      // big chunks first
    const int causal = *causal_p;
    float tau = __expf(*log_tau_p);
    tau = fminf(fmaxf(tau, 0.1f), 5.0f);
    const float inv_tau = 1.0f / tau;
    const float thr = fminf(fmaxf(*thr_p, 0.01f), 0.99f);

    const int T   = causal ? ((c >> 2) + 1) : 32;
    const int row = threadIdx.x >> 4;           // 0..15 (16 lanes per row, contiguous)
    const int sc4 = (threadIdx.x & 15) * 4;     // col group of 4
    const int l   = c*16 + row;
    const float* prow = &phi[(h*Lz + l)*Sz];
    const float* urow = &u[(h*Lz + l)*Sz];
    const int*   hrow = &hm[l*Sz];

    // ---- pass 1: row max of d over open entries ----
    float md = -INFINITY;
    for (int t = 0; t < T; ++t) {
        const int s = t*64 + sc4;
        const float4 ph = *(const float4*)&prow[s];
        const float4 uv = *(const float4*)&urow[s];
        const int4   hv = *(const int4*)&hrow[s];
        const float pa[4] = {ph.x, ph.y, ph.z, ph.w};
        const float ua[4] = {uv.x, uv.y, uv.z, uv.w};
        const int   ha[4] = {hv.x, hv.y, hv.z, hv.w};
#pragma unroll
        for (int j = 0; j < 4; ++j) {
            const float g  = __logf((ua[j] + 1e-8f) * fast_rcp(1.0f - ua[j] + 1e-8f));
            const float z  = (g + pa[j]) * inv_tau;
            const float sg = fast_rcp(1.0f + __expf(-z));
            const float d  = 1250.0f * fminf(sg - thr, 0.0f);  // scale*1e4/8 folded
            const bool open = (ha[j] != 0) && !(causal && (s + j > l));
            if (open) md = fmaxf(md, d);
        }
    }
#pragma unroll
    for (int o = 1; o < 16; o <<= 1)
        md = fmaxf(md, __shfl_xor(md, o, 16));  // diagonal always open -> md finite

    // ---- pass 2 (reverse, L2 LRU-friendly): store shifted bf16 ----
    const int hstride = causal ? 2112 : 4096;
    unsigned short* dbase = dag + (h*hstride + tile_base_of_chunk(c, causal))*1024
                                + row*64 + sc4;
    for (int t = T - 1; t >= 0; --t) {
        const int s = t*64 + sc4;
        const float4 ph = *(const float4*)&prow[s];
        const float4 uv = *(const float4*)&urow[s];
        const int4   hv = *(const int4*)&hrow[s];
        const float pa[4] = {ph.x, ph.y, ph.z, ph.w};
        const float ua[4] = {uv.x, uv.y, uv.z, uv.w};
        const int   ha[4] = {hv.x, hv.y, hv.z, hv.w};
        unsigned short o4[4];
#pragma unroll
        for (int j = 0; j < 4; ++j) {
            const float g  = __logf((ua[j] + 1e-8f) * fast_rcp(1.0f - ua[j] + 1e-8f));
            const float z  = (g + pa[j]) * inv_tau;
            const float sg = fast_rcp(1.0f + __expf(-z));
            const float d  = 1250.0f * fminf(sg - thr, 0.0f);
            const bool open = (ha[j] != 0) && !(causal && (s + j > l));
            o4[j] = open ? (unsigned short)f2bf(d - md) : (unsigned short)0xFF80u;
        }
        unsigned short* dst = dbase + t*1024;
        dst[0] = o4[0]; dst[1] = o4[1]; dst[2] = o4[2]; dst[3] = o4[3];
    }
}

// ---------------- main: flash attention, shift-folded no-max softmax ----------------
// grid 2048: h = blk&7 (XCD affinity), b = (blk>>3)&1, c = 127-(blk>>4) (big first).
// 8 waves = 8 S-segments of one (b,h,c); epilogue sums O and l across waves -> final out.
__global__ __launch_bounds__(512, 4) void attn_main(
    const unsigned short* __restrict__ dag, const int* __restrict__ causal_p,
    const short* __restrict__ qp, const short* __restrict__ kp,
    const short* __restrict__ vt, float* __restrict__ out)
{
    const int lane = threadIdx.x & 63;
    const int seg  = threadIdx.x >> 6;          // 0..7, also wave slot
    const int h    = blockIdx.x & 7;
    const int b    = (blockIdx.x >> 3) & 1;
    const int c    = 127 - (blockIdx.x >> 4);
    const int l_base = c * 16;
    const int ln   = lane & 15;
    const int quad = lane >> 4;

    const int causal = *causal_p;
    const int T = causal ? ((c >> 2) + 1) : 32;
    const int hstride = causal ? 2112 : 4096;
    const unsigned short* dbase = dag + (h*hstride + tile_base_of_chunk(c, causal))*1024
                                      + (quad*4)*64 + ln;

    // Q fragments (A-layout), resident
    short8 qf[2];
#pragma unroll
    for (int k = 0; k < 2; ++k)
        qf[k] = *(const short8*)&qp[((b*Hz + h)*Lz + l_base + ln)*Ez + k*32 + quad*8];

    f32x4 O[4];
    float l_r[4];
#pragma unroll
    for (int ne = 0; ne < 4; ++ne) { f32x4 z = {0.f,0.f,0.f,0.f}; O[ne] = z; }
#pragma unroll
    for (int r = 0; r < 4; ++r) l_r[r] = 0.f;

    // per-wave region: P scratch (16x72 bf16 = 2304B) unioned with O slab (16x64 f32 = 4096B)
    __shared__ __align__(16) char shm[8 * 4608];
    __shared__ float lslab[8][16];
    short* myp = (short*)(shm + seg*4608);

    auto lddag = [&](int t, unsigned (&D)[16]) {
        const unsigned short* dp = dbase + t*1024;
#pragma unroll
        for (int nt = 0; nt < 4; ++nt)
#pragma unroll
            for (int r = 0; r < 4; ++r)
                D[nt*4+r] = dp[r*64 + nt*16];
    };

    auto process = [&](int t, const unsigned (&D)[16]) {
        const short* kbase = &kp[((b*Hz + h)*Sz + t*64 + ln)*Ez + quad*8];
        f32x4 Sc[4];
#pragma unroll
        for (int nt = 0; nt < 4; ++nt) {
            const short8 k0 = *(const short8*)&kbase[nt*16*Ez];
            const short8 k1 = *(const short8*)&kbase[nt*16*Ez + 32];
            f32x4 z4 = {0.f,0.f,0.f,0.f};
            z4 = __builtin_amdgcn_mfma_f32_16x16x32_bf16(qf[0], k0, z4, 0, 0, 0);
            Sc[nt] = __builtin_amdgcn_mfma_f32_16x16x32_bf16(qf[1], k1, z4, 0, 0, 0);
        }
        // p = exp(qk/8 + dag_shifted); row argmax entry has dag_shifted = 0 ->
        // den >= exp(min qk/8) > 0, and qk/8 <= ~6 -> no overflow either.
#pragma unroll
        for (int nt = 0; nt < 4; ++nt)
#pragma unroll
            for (int r = 0; r < 4; ++r) {
                const float dg = __builtin_bit_cast(float, D[nt*4+r] << 16); // bf16->f32
                const float p  = __expf(Sc[nt][r] + dg);                     // exp(-inf)=0
                l_r[r] += p;
                myp[(quad*4 + r)*72 + nt*16 + ln] = f2bf(p);                 // C-layout -> LDS
            }
        const short8 pa0 = *(const short8*)&myp[ln*72 + quad*8];             // A-layout
        const short8 pa1 = *(const short8*)&myp[ln*72 + 32 + quad*8];
        const short* vb = &vt[((b*Hz + h)*Ez + ln)*Sz + t*64 + quad*8];
#pragma unroll
        for (int ne = 0; ne < 4; ++ne) {
            const short8 v0 = *(const short8*)&vb[ne*16*Sz];
            const short8 v1 = *(const short8*)&vb[ne*16*Sz + 32];
            O[ne] = __builtin_amdgcn_mfma_f32_16x16x32_bf16(pa0, v0, O[ne], 0, 0, 0);
            O[ne] = __builtin_amdgcn_mfma_f32_16x16x32_bf16(pa1, v1, O[ne], 0, 0, 0);
        }
    };

    // software-pipelined: prefetch next tile's dag while computing current
    unsigned DA[16], DB[16];
    int t = seg;
    if (t < T) lddag(t, DA);
    int parity = 0;
    for (; t < T; t += 8, parity ^= 1) {
        if (!parity) { if (t + 8 < T) lddag(t + 8, DB); process(t, DA); }
        else         { if (t + 8 < T) lddag(t + 8, DA); process(t, DB); }
    }

    // ---- epilogue: row-sum l across the 16 lanes of each quad-row ----
#pragma unroll
    for (int r = 0; r < 4; ++r) {
        float lv = l_r[r];
#pragma unroll
        for (int o = 1; o < 16; o <<= 1) lv += __shfl_xor(lv, o, 16);
        l_r[r] = lv;
    }
    // own-wave region reuse: P scratch -> O slab (no cross-wave hazard)
    float* fo = (float*)(shm + seg*4608);
#pragma unroll
    for (int ne = 0; ne < 4; ++ne)
#pragma unroll
        for (int r = 0; r < 4; ++r)
            fo[(quad*4 + r)*64 + ne*16 + ln] = O[ne][r];
    if (ln == 0) {
#pragma unroll
        for (int r = 0; r < 4; ++r) lslab[seg][quad*4 + r] = l_r[r];
    }
    __syncthreads();

    // merge 8 waves: out = (sum_w O_w) / (sum_w l_w); shift folded in dag is
    // row-uniform across waves, so plain sums are exact.
    const int row = threadIdx.x >> 5;           // 0..15
    const int e   = (threadIdx.x & 31) * 2;     // 0..62
    float den = 0.f, a0 = 0.f, a1 = 0.f;
#pragma unroll
    for (int w = 0; w < 8; ++w) {
        den += lslab[w][row];
        const float* fw = (const float*)(shm + w*4608) + row*64 + e;
        a0 += fw[0];
        a1 += fw[1];
    }
    const float rd = 1.0f / den;
    float2 res; res.x = a0 * rd; res.y = a1 * rd;
    *(float2*)&out[((b*Lz + l_base + row)*Hz + h)*Ez + e] = res;
}

extern "C" void kernel_launch(void* const* d_in, const int* in_sizes, int n_in,
                              void* d_out, int out_size, void* d_ws, size_t ws_size,
                              hipStream_t stream)
{
    const float* q    = (const float*)d_in[0];
    const float* k    = (const float*)d_in[1];
    const float* v    = (const float*)d_in[2];
    const int*   caus = (const int*)d_in[6];
    const int*   hm   = (const int*)d_in[7];
    const float* phi  = (const float*)d_in[8];
    const float* ltau = (const float*)d_in[9];
    const float* thr  = (const float*)d_in[10];
    const float* u    = (const float*)d_in[11];

    char* ws = (char*)d_ws;
    short*          qp  = (short*)(ws);                         //  4 MB
    short*          kp  = (short*)(ws + (size_t)( 4u << 20));   //  4 MB
    short*          vt  = (short*)(ws + (size_t)( 8u << 20));   //  4 MB
    unsigned short* dag = (unsigned short*)(ws + (size_t)(12u << 20)); // 33 MB packed causal

    pack_qk <<<2048, 256, 0, stream>>>(q, k, qp, kp);
    pack_vt <<<1024, 256, 0, stream>>>(v, vt);
    mask_k  <<<1024, 256, 0, stream>>>(phi, u, hm, caus, ltau, thr, dag);
    attn_main<<<2048, 512, 0, stream>>>(dag, caus, qp, kp, vt, (float*)d_out);
}